// Round 1
// baseline (129.615 us; speedup 1.0000x reference)
//
#include <hip/hip_runtime.h>
#include <math.h>

#define BB 8
#define TT 4096
#define DD 2048
#define THREADS 512          // 8 waves; D/THREADS = 4 floats/thread
#define NWAVES (THREADS / 64)

__device__ __forceinline__ float fast_tanh(float a) {
    // tanh(a) = 1 - 2/(exp(2a)+1); __expf -> v_exp_f32, saturates cleanly:
    // a -> +inf: e=inf -> 1; a -> -inf: e=0 -> -1.
    float e = __expf(2.0f * a);
    return 1.0f - 2.0f / (e + 1.0f);
}

__device__ __forceinline__ float gelu_tanh(float x) {
    const float c = 0.7978845608028654f;  // sqrt(2/pi)
    float inner = c * (x + 0.044715f * x * x * x);
    return 0.5f * x * (1.0f + fast_tanh(inner));
}

__global__ __launch_bounds__(THREADS) void gelu275_fused(
    const float* __restrict__ x,          // [B,T,D]
    const float* __restrict__ log_k_pos,  // [1]
    const float* __restrict__ pos_buf,    // [T,D]
    const float* __restrict__ pos_facil,  // [T]
    float* __restrict__ out)              // [B,T,D]
{
    const int t    = blockIdx.x;
    const int tid  = threadIdx.x;
    const int lane = tid & 63;
    const int wave = tid >> 6;

    __shared__ float red[NWAVES * 17];   // per-wave partials: pn2 + dot[8] + yn2[8]
    __shared__ float s_gate[BB];

    // ---- load pos_buf row slice (4 floats/thread, coalesced float4) ----
    const float4 p4 = *reinterpret_cast<const float4*>(
        pos_buf + (size_t)t * DD + (size_t)tid * 4);
    const float pp[4] = {p4.x, p4.y, p4.z, p4.w};
    float pn2 = pp[0]*pp[0] + pp[1]*pp[1] + pp[2]*pp[2] + pp[3]*pp[3];

    // ---- gelu + per-row partial dot / norm, y kept in registers ----
    float y[BB][4];
    float dotp[BB];
    float yn2[BB];
#pragma unroll
    for (int b = 0; b < BB; ++b) {
        const float4 x4 = *reinterpret_cast<const float4*>(
            x + ((size_t)b * TT + t) * DD + (size_t)tid * 4);
        const float xs[4] = {x4.x, x4.y, x4.z, x4.w};
        float d = 0.0f, n = 0.0f;
#pragma unroll
        for (int j = 0; j < 4; ++j) {
            float yv = gelu_tanh(xs[j]);
            y[b][j] = yv;
            d += yv * pp[j];
            n += yv * yv;
        }
        dotp[b] = d;
        yn2[b]  = n;
    }

    // ---- wave-level butterfly reduction of 17 partials ----
#pragma unroll
    for (int off = 32; off; off >>= 1) {
        pn2 += __shfl_xor(pn2, off);
#pragma unroll
        for (int b = 0; b < BB; ++b) {
            dotp[b] += __shfl_xor(dotp[b], off);
            yn2[b]  += __shfl_xor(yn2[b],  off);
        }
    }
    if (lane == 0) {
        red[wave * 17 + 0] = pn2;
#pragma unroll
        for (int b = 0; b < BB; ++b) {
            red[wave * 17 + 1 + b] = dotp[b];
            red[wave * 17 + 9 + b] = yn2[b];
        }
    }
    __syncthreads();

    // ---- final cross-wave reduce + gate computation on thread 0 ----
    if (tid == 0) {
        float P = 0.0f;
        float Dt[BB], Yn[BB];
#pragma unroll
        for (int b = 0; b < BB; ++b) { Dt[b] = 0.0f; Yn[b] = 0.0f; }
        for (int w = 0; w < NWAVES; ++w) {
            P += red[w * 17 + 0];
#pragma unroll
            for (int b = 0; b < BB; ++b) {
                Dt[b] += red[w * 17 + 1 + b];
                Yn[b] += red[w * 17 + 9 + b];
            }
        }
        const float kp = fminf(fmaxf(expf(log_k_pos[0]), 0.01f), 5.0f);
        const float pnorm = fmaxf(sqrtf(P), 1e-12f);

        float sim[BB];
        float simsum = 0.0f;
#pragma unroll
        for (int b = 0; b < BB; ++b) {
            float ynorm = fmaxf(sqrtf(Yn[b]), 1e-12f);
            sim[b] = Dt[b] / (ynorm * pnorm);
            simsum += sim[b];
        }
        const bool  fire  = (simsum * (1.0f / BB)) > 0.85f;
        const float pf    = pos_facil[t];
        const float facil = fire ? fminf(pf * 2.0f, 16.0f) : pf;
#pragma unroll
        for (int b = 0; b < BB; ++b) {
            s_gate[b] = fminf(1.0f + kp * (facil - 1.0f) * sim[b], 8.0f);
        }
    }
    __syncthreads();

    // ---- gated write-out (float4, coalesced) ----
#pragma unroll
    for (int b = 0; b < BB; ++b) {
        const float g = s_gate[b];
        float4 o;
        o.x = y[b][0] * g;
        o.y = y[b][1] * g;
        o.z = y[b][2] * g;
        o.w = y[b][3] * g;
        *reinterpret_cast<float4*>(
            out + ((size_t)b * TT + t) * DD + (size_t)tid * 4) = o;
    }
}

extern "C" void kernel_launch(void* const* d_in, const int* in_sizes, int n_in,
                              void* d_out, int out_size, void* d_ws, size_t ws_size,
                              hipStream_t stream) {
    const float* x          = (const float*)d_in[0];
    const float* log_k_pos  = (const float*)d_in[1];
    const float* pos_buf    = (const float*)d_in[2];
    const float* pos_facil  = (const float*)d_in[3];
    float* out              = (float*)d_out;

    dim3 grid(TT);
    dim3 block(THREADS);
    gelu275_fused<<<grid, block, 0, stream>>>(x, log_k_pos, pos_buf, pos_facil, out);
}